// Round 4
// baseline (115.434 us; speedup 1.0000x reference)
//
#include <hip/hip_runtime.h>

// out[j,i] = sum_k exp(-(x_k - i/512)^2 * 5000) * exp(-(y_k - j/512)^2 * 5000)
// 1024 points (8 curves x 128 steps), 512x512 fp32 output.
//
// Single fused kernel, grid (8,8,8) = 512 blocks (2/CU):
//   - each block: 64x64 tile x 128-wide K-slice, 4x4 micro-tile/thread
//   - partials -> d_ws tile-contiguously (plain float4 stores)
//   - last-block-per-tile (device-scope ticket + agent fences) reduces the
//     8 slices straight into d_out. No second dispatch, no atomics on out.

constexpr int RES_   = 512;
constexpr int TILE   = 64;             // output tile edge
constexpr int KSPLIT = 8;
constexpr int KB     = 1024 / KSPLIT;  // 128 K per block
constexpr int KC     = 64;             // K chunk staged in LDS
constexpr int NTX    = RES_ / TILE;    // 8 tiles per axis

__global__ __launch_bounds__(256)
void bezier_fused(const float* __restrict__ curves, float* __restrict__ out,
                  unsigned int* __restrict__ tickets, float* __restrict__ part) {
    __shared__ float xs[KB], ys[KB];
    __shared__ __align__(16) float ex_s[KC][TILE];   // 16 KB
    __shared__ __align__(16) float ey_s[KC][TILE];   // 16 KB
    __shared__ unsigned int s_old;

    const int tid     = threadIdx.x;
    const int ibase   = blockIdx.x * TILE;   // output columns i
    const int jbase   = blockIdx.y * TILE;   // output rows j
    const int tile_id = blockIdx.y * NTX + blockIdx.x;
    const int kbase   = blockIdx.z * KB;     // K slice

    // --- evaluate Bezier sample points (de Casteljau, fp32), threads 0..127 ---
    if (tid < KB) {
        int p = kbase + tid;                       // global point index
        int c = p >> 7;                            // curve 0..7
        float t = (float)(p & 127) * (1.0f / 127.0f);
        const float* cp = curves + c * 8;          // 4 control points x (x,y)
        float p0x = cp[0], p0y = cp[1];
        float p1x = cp[2], p1y = cp[3];
        float p2x = cp[4], p2y = cp[5];
        float p3x = cp[6], p3y = cp[7];
        float a01x = p0x + (p1x - p0x) * t, a01y = p0y + (p1y - p0y) * t;
        float a12x = p1x + (p2x - p1x) * t, a12y = p1y + (p2y - p1y) * t;
        float a23x = p2x + (p3x - p2x) * t, a23y = p2y + (p3y - p2y) * t;
        float qax = a01x + (a12x - a01x) * t, qay = a01y + (a12y - a01y) * t;
        float qbx = a12x + (a23x - a12x) * t, qby = a12y + (a23y - a12y) * t;
        xs[tid] = qax + (qbx - qax) * t;
        ys[tid] = qay + (qby - qay) * t;
    }
    __syncthreads();

    const int it = tid & 15, jt = tid >> 4;
    const int ib = it * 4, jb = jt * 4;    // 4x4 micro-tile origin in tile
    float acc[4][4];
#pragma unroll
    for (int r = 0; r < 4; ++r)
#pragma unroll
        for (int c = 0; c < 4; ++c) acc[r][c] = 0.0f;

    for (int chunk = 0; chunk < KB / KC; ++chunk) {
        // --- stage exp tiles, float4 LDS writes: 4 float4s per thread/array ---
#pragma unroll
        for (int e = 0; e < (KC * TILE) / (256 * 4); ++e) {
            int idx4 = (e * 256 + tid) * 4;        // float index
            int kk   = idx4 >> 6;                  // TILE == 64
            int ii   = idx4 & 63;
            float xv = xs[chunk * KC + kk];        // wave-uniform
            float yv = ys[chunk * KC + kk];
            float g0 = (float)(ibase + ii) * (1.0f / 512.0f);
            float h0 = (float)(jbase + ii) * (1.0f / 512.0f);
            float4 vx, vy;
            {
                float d0 = xv - g0, d1 = xv - (g0 + 1.0f/512.0f),
                      d2 = xv - (g0 + 2.0f/512.0f), d3 = xv - (g0 + 3.0f/512.0f);
                vx = make_float4(__expf(d0*d0*-5000.0f), __expf(d1*d1*-5000.0f),
                                 __expf(d2*d2*-5000.0f), __expf(d3*d3*-5000.0f));
                float e0 = yv - h0, e1 = yv - (h0 + 1.0f/512.0f),
                      e2 = yv - (h0 + 2.0f/512.0f), e3 = yv - (h0 + 3.0f/512.0f);
                vy = make_float4(__expf(e0*e0*-5000.0f), __expf(e1*e1*-5000.0f),
                                 __expf(e2*e2*-5000.0f), __expf(e3*e3*-5000.0f));
            }
            *reinterpret_cast<float4*>(&ex_s[kk][ii]) = vx;
            *reinterpret_cast<float4*>(&ey_s[kk][ii]) = vy;
        }
        __syncthreads();

        // --- 4x4 outer-product accumulation over KC ---
#pragma unroll 4
        for (int kk = 0; kk < KC; ++kk) {
            const float4 a = *reinterpret_cast<const float4*>(&ex_s[kk][ib]);
            const float4 b = *reinterpret_cast<const float4*>(&ey_s[kk][jb]);
            acc[0][0] += b.x * a.x; acc[0][1] += b.x * a.y;
            acc[0][2] += b.x * a.z; acc[0][3] += b.x * a.w;
            acc[1][0] += b.y * a.x; acc[1][1] += b.y * a.y;
            acc[1][2] += b.y * a.z; acc[1][3] += b.y * a.w;
            acc[2][0] += b.z * a.x; acc[2][1] += b.z * a.y;
            acc[2][2] += b.z * a.z; acc[2][3] += b.z * a.w;
            acc[3][0] += b.w * a.x; acc[3][1] += b.w * a.y;
            acc[3][2] += b.w * a.z; acc[3][3] += b.w * a.w;
        }
        __syncthreads();
    }

    // --- store partial tile (tile-contiguous), plain float4 stores ---
    float* pt = part + ((size_t)tile_id * KSPLIT + blockIdx.z) * (TILE * TILE);
#pragma unroll
    for (int r = 0; r < 4; ++r) {
        *reinterpret_cast<float4*>(&pt[(jb + r) * TILE + ib]) =
            make_float4(acc[r][0], acc[r][1], acc[r][2], acc[r][3]);
    }

    // --- release: make stores visible at agent scope, then take ticket ---
    __threadfence();
    __syncthreads();
    if (tid == 0) s_old = atomicAdd(&tickets[tile_id], 1u);
    __syncthreads();

    if (s_old == KSPLIT - 1) {
        // --- last block of this tile: acquire, reduce 8 slices -> out ---
        __threadfence();
        const float4* p4 = reinterpret_cast<const float4*>(
            part + (size_t)tile_id * KSPLIT * (TILE * TILE));
#pragma unroll
        for (int e = 0; e < (TILE * TILE) / (256 * 4); ++e) {
            int idx = e * 256 + tid;               // float4 index within slice
            float4 s = p4[idx];
#pragma unroll
            for (int z = 1; z < KSPLIT; ++z) {
                float4 v = p4[z * (TILE * TILE / 4) + idx];
                s.x += v.x; s.y += v.y; s.z += v.z; s.w += v.w;
            }
            int fi   = idx * 4;
            int j_in = fi >> 6;                    // TILE == 64
            int i_in = fi & 63;
            *reinterpret_cast<float4*>(&out[(jbase + j_in) * RES_ + ibase + i_in]) = s;
        }
    }
}

extern "C" void kernel_launch(void* const* d_in, const int* in_sizes, int n_in,
                              void* d_out, int out_size, void* d_ws, size_t ws_size,
                              hipStream_t stream) {
    const float* curves = (const float*)d_in[0];
    float* out = (float*)d_out;

    unsigned int* tickets = (unsigned int*)d_ws;                  // 64 x u32
    float* part = (float*)((char*)d_ws + 4096);                   // 8 MB partials

    // zero the tickets (graph-capturable); ws is re-poisoned 0xAA each iter
    hipMemsetAsync(tickets, 0, (RES_ / TILE) * (RES_ / TILE) * sizeof(unsigned int), stream);

    dim3 grid(NTX, NTX, KSPLIT);                   // (8, 8, 8) = 512 blocks
    bezier_fused<<<grid, dim3(256), 0, stream>>>(curves, out, tickets, part);
}

// Round 5
// 71.309 us; speedup vs baseline: 1.6188x; 1.6188x over previous
//
#include <hip/hip_runtime.h>

// out[j,i] = sum_k exp(-(x_k - i/512)^2 * 5000) * exp(-(y_k - j/512)^2 * 5000)
// 1024 points (8 curves x 128 steps), 512x512 fp32 output.
//
// K1: grid (8,8,16) = 1024 blocks (4 blocks/CU, 16 waves/CU): each block
//     computes a 64x64 tile over a 64-wide K-slice (single LDS chunk, exactly
//     2 barriers), 4x4 micro-tile/thread, partials -> d_ws as float4 stores.
// K2: 16-way reduce of partials -> d_out (fully overwrites d_out).
// No atomics, no device-scope fences (R4 showed per-block __threadfence
// cache-maintenance serializes in TCC: 512 blocks -> +45 us).

constexpr int RES_   = 512;
constexpr int TILE   = 64;             // output tile edge
constexpr int KSPLIT = 16;
constexpr int KB     = 1024 / KSPLIT;  // 64 K per block (single LDS chunk)

__global__ __launch_bounds__(256)
void bezier_partial(const float* __restrict__ curves, float* __restrict__ part) {
    __shared__ float xs[KB], ys[KB];
    __shared__ __align__(16) float ex_s[KB][TILE];   // 16 KB
    __shared__ __align__(16) float ey_s[KB][TILE];   // 16 KB

    const int tid   = threadIdx.x;
    const int ibase = blockIdx.x * TILE;   // output columns i
    const int jbase = blockIdx.y * TILE;   // output rows j
    const int kbase = blockIdx.z * KB;     // K slice

    // --- evaluate Bezier sample points (de Casteljau, fp32), threads 0..63 ---
    if (tid < KB) {
        int p = kbase + tid;                       // global point index
        int c = p >> 7;                            // curve 0..7
        float t = (float)(p & 127) * (1.0f / 127.0f);
        const float* cp = curves + c * 8;          // 4 control points x (x,y)
        float p0x = cp[0], p0y = cp[1];
        float p1x = cp[2], p1y = cp[3];
        float p2x = cp[4], p2y = cp[5];
        float p3x = cp[6], p3y = cp[7];
        float a01x = p0x + (p1x - p0x) * t, a01y = p0y + (p1y - p0y) * t;
        float a12x = p1x + (p2x - p1x) * t, a12y = p1y + (p2y - p1y) * t;
        float a23x = p2x + (p3x - p2x) * t, a23y = p2y + (p3y - p2y) * t;
        float qax = a01x + (a12x - a01x) * t, qay = a01y + (a12y - a01y) * t;
        float qbx = a12x + (a23x - a12x) * t, qby = a12y + (a23y - a12y) * t;
        xs[tid] = qax + (qbx - qax) * t;
        ys[tid] = qay + (qby - qay) * t;
    }
    __syncthreads();

    // --- stage exp tiles, float4 LDS writes: 4 float4s per thread per array ---
#pragma unroll
    for (int e = 0; e < (KB * TILE) / (256 * 4); ++e) {
        int idx4 = (e * 256 + tid) * 4;        // float index
        int kk   = idx4 >> 6;                  // TILE == 64
        int ii   = idx4 & 63;
        float xv = xs[kk];                     // wave-uniform -> LDS broadcast
        float yv = ys[kk];
        float g0 = (float)(ibase + ii) * (1.0f / 512.0f);
        float h0 = (float)(jbase + ii) * (1.0f / 512.0f);
        float d0 = xv - g0, d1 = xv - (g0 + 1.0f/512.0f),
              d2 = xv - (g0 + 2.0f/512.0f), d3 = xv - (g0 + 3.0f/512.0f);
        float4 vx = make_float4(__expf(d0*d0*-5000.0f), __expf(d1*d1*-5000.0f),
                                __expf(d2*d2*-5000.0f), __expf(d3*d3*-5000.0f));
        float e0 = yv - h0, e1 = yv - (h0 + 1.0f/512.0f),
              e2 = yv - (h0 + 2.0f/512.0f), e3 = yv - (h0 + 3.0f/512.0f);
        float4 vy = make_float4(__expf(e0*e0*-5000.0f), __expf(e1*e1*-5000.0f),
                                __expf(e2*e2*-5000.0f), __expf(e3*e3*-5000.0f));
        *reinterpret_cast<float4*>(&ex_s[kk][ii]) = vx;
        *reinterpret_cast<float4*>(&ey_s[kk][ii]) = vy;
    }
    __syncthreads();

    const int it = tid & 15, jt = tid >> 4;
    const int ib = it * 4, jb = jt * 4;    // 4x4 micro-tile origin in tile
    float acc[4][4];
#pragma unroll
    for (int r = 0; r < 4; ++r)
#pragma unroll
        for (int c = 0; c < 4; ++c) acc[r][c] = 0.0f;

    // --- 4x4 outer-product accumulation over KB ---
#pragma unroll 4
    for (int kk = 0; kk < KB; ++kk) {
        const float4 a = *reinterpret_cast<const float4*>(&ex_s[kk][ib]);
        const float4 b = *reinterpret_cast<const float4*>(&ey_s[kk][jb]);
        acc[0][0] += b.x * a.x; acc[0][1] += b.x * a.y;
        acc[0][2] += b.x * a.z; acc[0][3] += b.x * a.w;
        acc[1][0] += b.y * a.x; acc[1][1] += b.y * a.y;
        acc[1][2] += b.y * a.z; acc[1][3] += b.y * a.w;
        acc[2][0] += b.z * a.x; acc[2][1] += b.z * a.y;
        acc[2][2] += b.z * a.z; acc[2][3] += b.z * a.w;
        acc[3][0] += b.w * a.x; acc[3][1] += b.w * a.y;
        acc[3][2] += b.w * a.z; acc[3][3] += b.w * a.w;
    }

    // --- store partial tile: plain coalesced float4 stores, no atomics ---
    float* slice = part + (size_t)blockIdx.z * (RES_ * RES_);
#pragma unroll
    for (int r = 0; r < 4; ++r) {
        int j = jbase + jb + r;
        *reinterpret_cast<float4*>(&slice[j * RES_ + ibase + ib]) =
            make_float4(acc[r][0], acc[r][1], acc[r][2], acc[r][3]);
    }
}

__global__ __launch_bounds__(256)
void reduce_k(const float* __restrict__ part, float* __restrict__ out) {
    int i = blockIdx.x * blockDim.x + threadIdx.x;   // float4 index, 65536 total
    const float4* p4 = reinterpret_cast<const float4*>(part);
    float4 s = p4[i];
#pragma unroll
    for (int z = 1; z < KSPLIT; ++z) {               // 16 independent loads
        float4 v = p4[(size_t)z * (RES_ * RES_ / 4) + i];
        s.x += v.x; s.y += v.y; s.z += v.z; s.w += v.w;
    }
    reinterpret_cast<float4*>(out)[i] = s;
}

extern "C" void kernel_launch(void* const* d_in, const int* in_sizes, int n_in,
                              void* d_out, int out_size, void* d_ws, size_t ws_size,
                              hipStream_t stream) {
    const float* curves = (const float*)d_in[0];
    float* out  = (float*)d_out;
    float* part = (float*)d_ws;   // 16 MB of partials

    dim3 grid(RES_ / TILE, RES_ / TILE, KSPLIT);     // (8, 8, 16) = 1024 blocks
    bezier_partial<<<grid, dim3(256), 0, stream>>>(curves, part);

    reduce_k<<<dim3(RES_ * RES_ / 4 / 256), dim3(256), 0, stream>>>(part, out);
}

// Round 6
// 60.650 us; speedup vs baseline: 1.9033x; 1.1758x over previous
//
#include <hip/hip_runtime.h>

// out[j,i] = sum_k exp(-(x_k - i/512)^2 * 5000) * exp(-(y_k - j/512)^2 * 5000)
// sigma = 0.01 -> 5.12 px: a point only influences +/-32 px (tail < 3e-9).
// Sparse gather: one block per 32x32 tile; evaluate all 1024 Bezier points,
// cull to the tile's +/-33px window, compact coords to LDS (unordered
// atomicAdd - summation order irrelevant), stage exp factors per 64-point
// chunk, 2x2 micro-tile accumulate. Single dispatch, direct store to d_out
// (full overwrite), no partials/reduce/memset/device fences.

constexpr int RES_ = 512;
constexpr int TILE = 32;               // output tile edge
constexpr int NPTS = 1024;
constexpr int CH   = 64;               // points staged per chunk
constexpr float RAD = 33.0f / 512.0f;  // truncation radius (33 px)

__global__ __launch_bounds__(256)
void bezier_sparse(const float* __restrict__ curves, float* __restrict__ out) {
    __shared__ float lx[NPTS], ly[NPTS];             // compacted survivor coords
    __shared__ int count;
    __shared__ __align__(16) float ex_s[CH][TILE];   // 8 KB
    __shared__ __align__(16) float ey_s[CH][TILE];   // 8 KB

    const int tid   = threadIdx.x;
    const int ibase = blockIdx.x * TILE;   // output columns i
    const int jbase = blockIdx.y * TILE;   // output rows j

    if (tid == 0) count = 0;
    __syncthreads();

    const float xlo = (float)ibase * (1.0f/512.0f) - RAD;
    const float xhi = (float)(ibase + TILE - 1) * (1.0f/512.0f) + RAD;
    const float ylo = (float)jbase * (1.0f/512.0f) - RAD;
    const float yhi = (float)(jbase + TILE - 1) * (1.0f/512.0f) + RAD;

    // --- evaluate 4 Bezier points per thread (de Casteljau), cull, compact ---
#pragma unroll
    for (int e = 0; e < NPTS / 256; ++e) {
        int p = e * 256 + tid;
        int c = p >> 7;                            // curve 0..7
        float t = (float)(p & 127) * (1.0f / 127.0f);
        const float* cp = curves + c * 8;
        float p0x = cp[0], p0y = cp[1];
        float p1x = cp[2], p1y = cp[3];
        float p2x = cp[4], p2y = cp[5];
        float p3x = cp[6], p3y = cp[7];
        float a01x = p0x + (p1x - p0x) * t, a01y = p0y + (p1y - p0y) * t;
        float a12x = p1x + (p2x - p1x) * t, a12y = p1y + (p2y - p1y) * t;
        float a23x = p2x + (p3x - p2x) * t, a23y = p2y + (p3y - p2y) * t;
        float qax = a01x + (a12x - a01x) * t, qay = a01y + (a12y - a01y) * t;
        float qbx = a12x + (a23x - a12x) * t, qby = a12y + (a23y - a12y) * t;
        float X = qax + (qbx - qax) * t;
        float Y = qay + (qby - qay) * t;
        if (X > xlo && X < xhi && Y > ylo && Y < yhi) {
            int idx = atomicAdd(&count, 1);        // LDS atomic, unordered ok
            lx[idx] = X;
            ly[idx] = Y;
        }
    }
    __syncthreads();
    const int M = count;

    const int it = tid & 15, jt = tid >> 4;
    const int ib2 = it * 2, jb2 = jt * 2;          // 2x2 micro-tile origin
    float a00 = 0.f, a01v = 0.f, a10 = 0.f, a11 = 0.f;

    for (int base = 0; base < M; base += CH) {
        const int chunk = (M - base < CH) ? (M - base) : CH;
        __syncthreads();                           // protect ex_s/ey_s reuse
        // --- stage exp factors: CH x TILE slots, 8 per thread per array ---
#pragma unroll
        for (int e = 0; e < (CH * TILE) / 256; ++e) {
            int idx = e * 256 + tid;
            int kk  = idx >> 5;                    // TILE == 32
            int ii  = idx & 31;
            if (kk < chunk) {
                float xv = lx[base + kk], yv = ly[base + kk];
                float dx = xv - (float)(ibase + ii) * (1.0f / 512.0f);
                float dy = yv - (float)(jbase + ii) * (1.0f / 512.0f);
                ex_s[kk][ii] = __expf(dx * dx * -5000.0f);
                ey_s[kk][ii] = __expf(dy * dy * -5000.0f);
            }
        }
        __syncthreads();

        // --- 2x2 outer-product accumulation over surviving points ---
#pragma unroll 4
        for (int k = 0; k < chunk; ++k) {
            const float2 a = *reinterpret_cast<const float2*>(&ex_s[k][ib2]);
            const float2 b = *reinterpret_cast<const float2*>(&ey_s[k][jb2]);
            a00 += b.x * a.x; a01v += b.x * a.y;
            a10 += b.y * a.x; a11  += b.y * a.y;
        }
    }

    // --- store 2x2 micro-tile directly to out (full coverage, no memset) ---
    const int j0 = jbase + jb2, i0 = ibase + ib2;
    *reinterpret_cast<float2*>(&out[(size_t)j0 * RES_ + i0])       = make_float2(a00, a01v);
    *reinterpret_cast<float2*>(&out[(size_t)(j0 + 1) * RES_ + i0]) = make_float2(a10, a11);
}

extern "C" void kernel_launch(void* const* d_in, const int* in_sizes, int n_in,
                              void* d_out, int out_size, void* d_ws, size_t ws_size,
                              hipStream_t stream) {
    const float* curves = (const float*)d_in[0];
    float* out = (float*)d_out;

    dim3 grid(RES_ / TILE, RES_ / TILE);           // (16, 16) = 256 blocks
    bezier_sparse<<<grid, dim3(256), 0, stream>>>(curves, out);
}

// Round 7
// 59.451 us; speedup vs baseline: 1.9417x; 1.0202x over previous
//
#include <hip/hip_runtime.h>

// out[j,i] = sum_k exp(-(x_k - i/512)^2 * 5000) * exp(-(y_k - j/512)^2 * 5000)
// sigma = 0.01 -> 5.12 px: a point only influences +/-32 px (tail < 3e-9).
// Sparse gather: one block per 32x32 tile; evaluate all 1024 Bezier points,
// cull to the tile's +/-33px window, wave-ballot compaction into LDS
// (1 atomic/wave, order irrelevant), sentinel-pad to a CH multiple so the
// staging + accumulate loops are branch-free, 2x2 micro-tile accumulate.
// Single dispatch, direct full-coverage store to d_out.

constexpr int RES_ = 512;
constexpr int TILE = 32;               // output tile edge
constexpr int NPTS = 1024;
constexpr int CH   = 64;               // points staged per chunk
constexpr float RAD = 33.0f / 512.0f;  // truncation radius (33 px)
constexpr float SENTINEL = 1.0e3f;     // far away -> exp flushes to exact 0

__global__ __launch_bounds__(256)
void bezier_sparse(const float* __restrict__ curves, float* __restrict__ out) {
    __shared__ float lx[NPTS + CH], ly[NPTS + CH];   // compacted + pad
    __shared__ int count;
    __shared__ __align__(16) float ex_s[CH][TILE];   // 8 KB
    __shared__ __align__(16) float ey_s[CH][TILE];   // 8 KB

    const int tid  = threadIdx.x;
    const int lane = tid & 63;
    const int ibase = blockIdx.x * TILE;   // output columns i
    const int jbase = blockIdx.y * TILE;   // output rows j

    if (tid == 0) count = 0;
    __syncthreads();

    const float xlo = (float)ibase * (1.0f/512.0f) - RAD;
    const float xhi = (float)(ibase + TILE - 1) * (1.0f/512.0f) + RAD;
    const float ylo = (float)jbase * (1.0f/512.0f) - RAD;
    const float yhi = (float)(jbase + TILE - 1) * (1.0f/512.0f) + RAD;

    // --- evaluate 4 Bezier points/thread (de Casteljau), ballot-compact ---
#pragma unroll
    for (int e = 0; e < NPTS / 256; ++e) {
        int p = e * 256 + tid;
        int c = p >> 7;                            // curve 0..7
        float t = (float)(p & 127) * (1.0f / 127.0f);
        const float* cp = curves + c * 8;
        float p0x = cp[0], p0y = cp[1];
        float p1x = cp[2], p1y = cp[3];
        float p2x = cp[4], p2y = cp[5];
        float p3x = cp[6], p3y = cp[7];
        float a01x = p0x + (p1x - p0x) * t, a01y = p0y + (p1y - p0y) * t;
        float a12x = p1x + (p2x - p1x) * t, a12y = p1y + (p2y - p1y) * t;
        float a23x = p2x + (p3x - p2x) * t, a23y = p2y + (p3y - p2y) * t;
        float qax = a01x + (a12x - a01x) * t, qay = a01y + (a12y - a01y) * t;
        float qbx = a12x + (a23x - a12x) * t, qby = a12y + (a23y - a12y) * t;
        float X = qax + (qbx - qax) * t;
        float Y = qay + (qby - qay) * t;

        bool keep = (X > xlo && X < xhi && Y > ylo && Y < yhi);
        unsigned long long mask = __ballot(keep);
        if (mask) {
            int nsurv  = __popcll(mask);
            int prefix = __popcll(mask & ((1ull << lane) - 1ull));
            int base_i = 0;
            if (lane == __ffsll((long long)mask) - 1)   // first active lane
                base_i = atomicAdd(&count, nsurv);      // 1 atomic per wave
            // broadcast base from that lane (readfirstlane over active lanes
            // of the atomic result is not uniform; use shuffle from leader)
            base_i = __shfl(base_i, __ffsll((long long)mask) - 1);
            if (keep) {
                lx[base_i + prefix] = X;
                ly[base_i + prefix] = Y;
            }
        }
    }
    __syncthreads();
    const int M = count;

    // --- sentinel-pad survivor list up to next CH multiple (branch-free loops)
    if (tid < CH) {
        lx[M + tid] = SENTINEL;
        ly[M + tid] = SENTINEL;
    }
    __syncthreads();

    const int it = tid & 15, jt = tid >> 4;
    const int ib2 = it * 2, jb2 = jt * 2;          // 2x2 micro-tile origin
    float a00 = 0.f, a01v = 0.f, a10 = 0.f, a11 = 0.f;

    const int Mp = (M + CH - 1) & ~(CH - 1);       // padded chunk count
    for (int base = 0; base < Mp; base += CH) {
        // --- stage exp factors: CH x TILE slots, branch-free, 8/thread ---
#pragma unroll
        for (int e = 0; e < (CH * TILE) / 256; ++e) {
            int idx = e * 256 + tid;
            int kk  = idx >> 5;                    // TILE == 32
            int ii  = idx & 31;
            float xv = lx[base + kk], yv = ly[base + kk];
            float dx = xv - (float)(ibase + ii) * (1.0f / 512.0f);
            float dy = yv - (float)(jbase + ii) * (1.0f / 512.0f);
            ex_s[kk][ii] = __expf(dx * dx * -5000.0f);   // sentinel -> 0
            ey_s[kk][ii] = __expf(dy * dy * -5000.0f);
        }
        __syncthreads();

        // --- 2x2 outer-product accumulation, fixed trip count ---
#pragma unroll 8
        for (int k = 0; k < CH; ++k) {
            const float2 a = *reinterpret_cast<const float2*>(&ex_s[k][ib2]);
            const float2 b = *reinterpret_cast<const float2*>(&ey_s[k][jb2]);
            a00 += b.x * a.x; a01v += b.x * a.y;
            a10 += b.y * a.x; a11  += b.y * a.y;
        }
        __syncthreads();                           // protect ex_s/ey_s reuse
    }

    // --- store 2x2 micro-tile directly to out (full coverage, no memset) ---
    const int j0 = jbase + jb2, i0 = ibase + ib2;
    *reinterpret_cast<float2*>(&out[(size_t)j0 * RES_ + i0])       = make_float2(a00, a01v);
    *reinterpret_cast<float2*>(&out[(size_t)(j0 + 1) * RES_ + i0]) = make_float2(a10, a11);
}

extern "C" void kernel_launch(void* const* d_in, const int* in_sizes, int n_in,
                              void* d_out, int out_size, void* d_ws, size_t ws_size,
                              hipStream_t stream) {
    const float* curves = (const float*)d_in[0];
    float* out = (float*)d_out;

    dim3 grid(RES_ / TILE, RES_ / TILE);           // (16, 16) = 256 blocks
    bezier_sparse<<<grid, dim3(256), 0, stream>>>(curves, out);
}